// Round 2
// baseline (413949.951 us; speedup 1.0000x reference)
//
#include <hip/hip_runtime.h>

#define Bq 32
#define Sq 2048
#define Iq 128
#define Hq 512
#define Oq 128
#define NWG 256
#define NT 256
#define KB 256  // k-block size staged in LDS (256*32*4B = 32KB)

__device__ __forceinline__ float sigmoidf_(float v) {
    return 1.0f / (1.0f + __expf(-v));
}

// Grid-wide barrier under a REGULAR launch (all NWG blocks co-resident).
// bar[0] = arrive counter, bar[1] = generation. Release/acquire chain:
// each block's data writes -> acq_rel RMW on cnt -> last arriver's release
// bump of gen -> acquire load of gen by waiters.
__device__ __forceinline__ void gridbar(int* bar, int target) {
    __syncthreads();
    if (threadIdx.x == 0) {
        __threadfence();
        int a = __hip_atomic_fetch_add(&bar[0], 1, __ATOMIC_ACQ_REL,
                                       __HIP_MEMORY_SCOPE_AGENT);
        if (a == NWG - 1) {
            __hip_atomic_store(&bar[0], 0, __ATOMIC_RELAXED,
                               __HIP_MEMORY_SCOPE_AGENT);
            __hip_atomic_fetch_add(&bar[1], 1, __ATOMIC_RELEASE,
                                   __HIP_MEMORY_SCOPE_AGENT);
        } else {
            while (__hip_atomic_load(&bar[1], __ATOMIC_ACQUIRE,
                                     __HIP_MEMORY_SCOPE_AGENT) < target) {
                __builtin_amdgcn_s_sleep(1);
            }
        }
        __threadfence();
    }
    __syncthreads();
}

// Stage g[b*rowStride + k0 + k] (k=0..K-1, b=0..31) into sst[k*32+b].
// [k][b] layout: lanes b=0..31 at fixed k hit 32 distinct banks.
__device__ __forceinline__ void stageK(float* sst, const float* __restrict__ g,
                                       long rowStride, int k0, int K) {
    __syncthreads();  // protect previous readers of sst
    int n4 = K >> 2;
    for (int i = threadIdx.x; i < 32 * n4; i += NT) {
        int b = i & 31;
        int k4 = i >> 5;
        const float4 v =
            *(const float4*)(g + (long)b * rowStride + k0 + (k4 << 2));
        int base = (k4 << 2) * 32 + b;
        sst[base] = v.x;
        sst[base + 32] = v.y;
        sst[base + 64] = v.z;
        sst[base + 96] = v.w;
    }
    __syncthreads();
}

__device__ __forceinline__ float dotK(const float* sst,
                                      const float* __restrict__ Wrow, int b,
                                      int K) {
    float a0 = 0.f, a1 = 0.f, a2 = 0.f, a3 = 0.f;
#pragma unroll 8
    for (int k = 0; k < K; k += 4) {
        float4 w = *(const float4*)(Wrow + k);
        a0 = fmaf(w.x, sst[(k) * 32 + b], a0);
        a1 = fmaf(w.y, sst[(k + 1) * 32 + b], a1);
        a2 = fmaf(w.z, sst[(k + 2) * 32 + b], a2);
        a3 = fmaf(w.w, sst[(k + 3) * 32 + b], a3);
    }
    return (a0 + a1) + (a2 + a3);
}

__global__ void bar_init(int* bar) {
    bar[0] = 0;
    bar[1] = 0;
}

__global__ __launch_bounds__(NT, 1) void gru_fused(
    const float* __restrict__ x, const float* __restrict__ h0in,
    const float* __restrict__ Wx0, const float* __restrict__ Wh0,
    const float* __restrict__ bh0, const float* __restrict__ Wx1,
    const float* __restrict__ Wh1, const float* __restrict__ bh1,
    const float* __restrict__ Why, const float* __restrict__ bhy,
    float* __restrict__ out, float* __restrict__ ws) {
    __shared__ float sst[KB * 32];  // 32 KB
    const int wg = blockIdx.x;
    const int tid = threadIdx.x;
    int* bar = (int*)(ws + 196608);
    int ep = 0;

    // workspace layout (floats)
    float* h0 = ws;              // [b*512+j]  layer0 state
    float* h1 = ws + 16384;      // layer1 state
    float* xzr0 = ws + 32768;    // [b*1024+j] x-side z,r for layer0 (cur step)
    float* xg0 = ws + 65536;     // [b*512+j]
    float* z0 = ws + 81920;
    float* rh0 = ws + 98304;
    float* hzr1 = ws + 114688;   // [b*1024+j]
    float* z1 = ws + 147456;
    float* rh1 = ws + 163840;
    float* xg1 = ws + 180224;

    // ---- pre-loop: init states; precompute xzr0 for t=0 ----
    if (wg < 86) {
        for (int i = wg * NT + tid; i < 2 * Bq * Hq; i += 86 * NT) {
            int b = i >> 10, l = (i >> 9) & 1, j = i & 511;
            float v = h0in[i];  // layout [b][l][h]
            (l ? h1 : h0)[b * Hq + j] = v;
        }
    } else {
        stageK(sst, x, (long)Sq * Iq, 0, Iq);  // x_0
        int lid = (wg - 86) * NT + tid;
        if (lid < Bq * 2 * Hq) {
            int b = lid & 31, j = lid >> 5;
            xzr0[b * 1024 + j] = dotK(sst, Wx0 + j * Iq, b, Iq);
        }
    }
    gridbar(bar, ++ep);

    for (int t = 0;; ++t) {
        // ---- phase A (also final epilogue at t==S) ----
        if (t == Sq) {
            if (wg < 128) {
                int i = wg * NT + tid;  // 32768 = B*L*H exactly
                int b = i >> 10, l = (i >> 9) & 1, j = i & 511;
                out[(size_t)Bq * Sq * Oq + i] = (l ? h1 : h0)[b * Hq + j];
            } else if (wg >= 240) {
                int lid = (wg - 240) * NT + tid;  // 4096 = B*O exactly
                int b = lid & 31, o = lid >> 5;
                float acc = 0.f;
                for (int kb = 0; kb < Hq; kb += KB) {
                    stageK(sst, h1, Hq, kb, KB);
                    acc += dotK(sst, Why + o * Hq + kb, b, KB);
                }
                out[((size_t)b * Sq + (Sq - 1)) * Oq + o] = acc + bhy[o];
            }
            break;
        }
        if (wg < 160) {
            // A1: z0, r0, rh0  (h-side zr matmul + precomputed x-side)
            int lid = wg * NT + tid;
            bool act = lid < Bq * 2 * Hq;
            int b = lid & 31, j = lid >> 5;
            float acc = 0.f;
            for (int kb = 0; kb < Hq; kb += KB) {
                stageK(sst, h0, Hq, kb, KB);
                if (act) acc += dotK(sst, Wh0 + j * Hq + kb, b, KB);
            }
            if (act) {
                float s = sigmoidf_(xzr0[b * 1024 + j] + acc + bh0[j]);
                if (j < Hq)
                    z0[b * Hq + j] = s;
                else
                    rh0[b * Hq + (j - Hq)] = s * h0[b * Hq + (j - Hq)];
            }
        } else if (wg < 240) {
            // A2: xg0 = x_t @ Wx0_g^T
            stageK(sst, x + (long)t * Iq, (long)Sq * Iq, 0, Iq);
            int lid = (wg - 160) * NT + tid;
            if (lid < Bq * Hq) {
                int b = lid & 31, j = lid >> 5;
                xg0[b * Hq + j] = dotK(sst, Wx0 + (2 * Hq + j) * Iq, b, Iq);
            }
        } else {
            // A3: y_{t-1} = s1_{t-1} @ Why^T + bhy
            int lid = (wg - 240) * NT + tid;  // 4096 threads = 4096 outputs
            int b = lid & 31, o = lid >> 5;
            float acc = 0.f;
            for (int kb = 0; kb < Hq; kb += KB) {
                stageK(sst, h1, Hq, kb, KB);
                acc += dotK(sst, Why + o * Hq + kb, b, KB);
            }
            if (t > 0)
                out[((size_t)b * Sq + (t - 1)) * Oq + o] = acc + bhy[o];
        }
        gridbar(bar, ++ep);

        // ---- phase B ----
        if (wg < 86) {
            // B1: g0, h0 update
            int lid = wg * NT + tid;
            bool act = lid < Bq * Hq;
            int b = lid & 31, j = lid >> 5;
            float acc = 0.f;
            for (int kb = 0; kb < Hq; kb += KB) {
                stageK(sst, rh0, Hq, kb, KB);
                if (act)
                    acc += dotK(sst, Wh0 + (2 * Hq + j) * Hq + kb, b, KB);
            }
            if (act) {
                float g = tanhf(xg0[b * Hq + j] + acc + bh0[2 * Hq + j]);
                float zz = z0[b * Hq + j];
                float hold = h0[b * Hq + j];
                h0[b * Hq + j] = zz * hold + (1.f - zz) * g;
            }
        } else {
            // B2: hzr1 = h1 @ Wh1_zr^T + bh1_zr
            int lid = (wg - 86) * NT + tid;
            bool act = lid < Bq * 2 * Hq;
            int b = lid & 31, j = lid >> 5;
            float acc = 0.f;
            for (int kb = 0; kb < Hq; kb += KB) {
                stageK(sst, h1, Hq, kb, KB);
                if (act) acc += dotK(sst, Wh1 + j * Hq + kb, b, KB);
            }
            if (act) hzr1[b * 1024 + j] = acc + bh1[j];
        }
        gridbar(bar, ++ep);

        // ---- phase C: both groups consume staged s0 (= updated h0) ----
        {
            int lid, nout;
            const float* Wrow;
            bool isC1 = wg < 170;
            if (isC1) {
                lid = wg * NT + tid;
                nout = Bq * 2 * Hq;
            } else {
                lid = (wg - 170) * NT + tid;
                nout = Bq * Hq;
            }
            bool act = lid < nout;
            int b = lid & 31, j = lid >> 5;
            Wrow = isC1 ? (Wx1 + j * Hq) : (Wx1 + (2 * Hq + j) * Hq);
            float acc = 0.f;
            for (int kb = 0; kb < Hq; kb += KB) {
                stageK(sst, h0, Hq, kb, KB);
                if (act) acc += dotK(sst, Wrow + kb, b, KB);
            }
            if (act) {
                if (isC1) {
                    float s = sigmoidf_(acc + hzr1[b * 1024 + j]);
                    if (j < Hq)
                        z1[b * Hq + j] = s;
                    else
                        rh1[b * Hq + (j - Hq)] = s * h1[b * Hq + (j - Hq)];
                } else {
                    xg1[b * Hq + j] = acc;
                }
            }
        }
        gridbar(bar, ++ep);

        // ---- phase D ----
        if (wg < 86) {
            // D1: g1, h1 update
            int lid = wg * NT + tid;
            bool act = lid < Bq * Hq;
            int b = lid & 31, j = lid >> 5;
            float acc = 0.f;
            for (int kb = 0; kb < Hq; kb += KB) {
                stageK(sst, rh1, Hq, kb, KB);
                if (act)
                    acc += dotK(sst, Wh1 + (2 * Hq + j) * Hq + kb, b, KB);
            }
            if (act) {
                float g = tanhf(xg1[b * Hq + j] + acc + bh1[2 * Hq + j]);
                float zz = z1[b * Hq + j];
                float hold = h1[b * Hq + j];
                h1[b * Hq + j] = zz * hold + (1.f - zz) * g;
            }
        } else if (t + 1 < Sq) {
            // D2: xzr0 for t+1
            stageK(sst, x + (long)(t + 1) * Iq, (long)Sq * Iq, 0, Iq);
            int lid = (wg - 86) * NT + tid;
            if (lid < Bq * 2 * Hq) {
                int b = lid & 31, j = lid >> 5;
                xzr0[b * 1024 + j] = dotK(sst, Wx0 + j * Iq, b, Iq);
            }
        }
        gridbar(bar, ++ep);
    }
}

extern "C" void kernel_launch(void* const* d_in, const int* in_sizes, int n_in,
                              void* d_out, int out_size, void* d_ws,
                              size_t ws_size, hipStream_t stream) {
    const float* x = (const float*)d_in[0];
    const float* h0in = (const float*)d_in[1];
    const float* Wx0 = (const float*)d_in[2];
    const float* Wh0 = (const float*)d_in[3];
    const float* bh0 = (const float*)d_in[4];
    const float* Wx1 = (const float*)d_in[5];
    const float* Wh1 = (const float*)d_in[6];
    const float* bh1 = (const float*)d_in[7];
    const float* Why = (const float*)d_in[8];
    const float* bhy = (const float*)d_in[9];
    float* out = (float*)d_out;
    float* ws = (float*)d_ws;
    int* bar = (int*)(ws + 196608);

    bar_init<<<1, 1, 0, stream>>>(bar);
    gru_fused<<<dim3(NWG), dim3(NT), 0, stream>>>(x, h0in, Wx0, Wh0, bh0, Wx1,
                                                  Wh1, bh1, Why, bhy, out, ws);
}

// Round 3
// 120591.284 us; speedup vs baseline: 3.4327x; 3.4327x over previous
//
#include <hip/hip_runtime.h>

#define Bq 32
#define Sq 2048
#define Iq 128
#define Hq 512
#define Oq 128
#define NWG 256
#define NT 256
#define KB 256
#define SSTRIDE (KB + 4)  // dword stride per b-row in LDS; +4 keeps 16B align, breaks bank pow2

__device__ __forceinline__ float sigmoidf_(float v) {
    return 1.0f / (1.0f + __expf(-v));
}

// Coherent-at-LLC data access (sc0 sc1), NO cache-maintenance fences.
__device__ __forceinline__ float ld_coh(const float* p) {
    return __hip_atomic_load(p, __ATOMIC_RELAXED, __HIP_MEMORY_SCOPE_AGENT);
}
__device__ __forceinline__ void st_coh(float* p, float v) {
    __hip_atomic_store(p, v, __ATOMIC_RELAXED, __HIP_MEMORY_SCOPE_AGENT);
}

// Fence-free tree barrier: 8 leaves (32 blocks each) -> root -> generation.
// Relaxed atomics only; explicit waitcnt orders resets/data before publishes.
// Each wave's pending stores drain at the __syncthreads s_barrier, so by the
// time thread 0 arrives, the whole block's coherent stores are at the LLC.
__device__ __forceinline__ void gridbar(int* bar, int target) {
    __syncthreads();
    if (threadIdx.x == 0) {
        asm volatile("s_waitcnt vmcnt(0) lgkmcnt(0)" ::: "memory");
        int* leaf = bar + ((blockIdx.x & 7) << 6);  // 256B apart
        int* root = bar + (8 << 6);
        int* gen = root + 64;
        int a = __hip_atomic_fetch_add(leaf, 1, __ATOMIC_RELAXED,
                                       __HIP_MEMORY_SCOPE_AGENT);
        if (a == 31) {
            __hip_atomic_store(leaf, 0, __ATOMIC_RELAXED,
                               __HIP_MEMORY_SCOPE_AGENT);
            asm volatile("s_waitcnt vmcnt(0)" ::: "memory");
            int r = __hip_atomic_fetch_add(root, 1, __ATOMIC_RELAXED,
                                           __HIP_MEMORY_SCOPE_AGENT);
            if (r == 7) {
                __hip_atomic_store(root, 0, __ATOMIC_RELAXED,
                                   __HIP_MEMORY_SCOPE_AGENT);
                asm volatile("s_waitcnt vmcnt(0)" ::: "memory");
                __hip_atomic_store(gen, target, __ATOMIC_RELAXED,
                                   __HIP_MEMORY_SCOPE_AGENT);
            }
        }
        while (__hip_atomic_load(gen, __ATOMIC_RELAXED,
                                 __HIP_MEMORY_SCOPE_AGENT) < target) {
            __builtin_amdgcn_s_sleep(1);
        }
    }
    __syncthreads();
}

// Stage 32 x 256 chunk of mutable ws state (coherent loads) into sst[b][k].
__device__ __forceinline__ void stage256(float* sst, const float* g,
                                         long rowStride, int k0) {
    __syncthreads();
    float4 v[8];
#pragma unroll
    for (int u = 0; u < 8; ++u) {
        int i = threadIdx.x + u * NT;
        int b = i & 31, k4 = i >> 5;
        const float* p = g + (long)b * rowStride + k0 + (k4 << 2);
        v[u].x = ld_coh(p);
        v[u].y = ld_coh(p + 1);
        v[u].z = ld_coh(p + 2);
        v[u].w = ld_coh(p + 3);
    }
#pragma unroll
    for (int u = 0; u < 8; ++u) {
        int i = threadIdx.x + u * NT;
        int b = i & 31, k4 = i >> 5;
        *(float4*)(sst + b * SSTRIDE + (k4 << 2)) = v[u];
    }
    __syncthreads();
}

// Stage 32 x 128 chunk of IMMUTABLE input x (plain cached loads).
__device__ __forceinline__ void stage128p(float* sst, const float* g,
                                          long rowStride) {
    __syncthreads();
#pragma unroll
    for (int u = 0; u < 4; ++u) {
        int i = threadIdx.x + u * NT;
        int b = i & 31, k4 = i >> 5;
        float4 v = *(const float4*)(g + (long)b * rowStride + (k4 << 2));
        *(float4*)(sst + b * SSTRIDE + (k4 << 2)) = v;
    }
    __syncthreads();
}

// dot of weight row (plain cached, wave-broadcast) vs staged column b.
__device__ __forceinline__ float dotC(const float* sst,
                                      const float* __restrict__ Wrow, int b,
                                      int K) {
    const float* s = sst + b * SSTRIDE;
    float a0 = 0.f, a1 = 0.f, a2 = 0.f, a3 = 0.f;
#pragma unroll 8
    for (int k = 0; k < K; k += 4) {
        float4 w = *(const float4*)(Wrow + k);
        float4 h = *(const float4*)(s + k);  // ds_read_b128
        a0 = fmaf(w.x, h.x, a0);
        a1 = fmaf(w.y, h.y, a1);
        a2 = fmaf(w.z, h.z, a2);
        a3 = fmaf(w.w, h.w, a3);
    }
    return (a0 + a1) + (a2 + a3);
}

__global__ void bar_init(int* bar) {
    for (int i = threadIdx.x; i < 1024; i += 256) bar[i] = 0;
}

__global__ __launch_bounds__(NT, 1) void gru_fused(
    const float* __restrict__ x, const float* __restrict__ h0in,
    const float* __restrict__ Wx0, const float* __restrict__ Wh0,
    const float* __restrict__ bh0, const float* __restrict__ Wx1,
    const float* __restrict__ Wh1, const float* __restrict__ bh1,
    const float* __restrict__ Why, const float* __restrict__ bhy,
    float* __restrict__ out, float* __restrict__ ws) {
    __shared__ float sst[32 * SSTRIDE];  // 33.3 KB
    const int wg = blockIdx.x;
    const int tid = threadIdx.x;
    int* bar = (int*)(ws + 180224);
    int ep = 0;

    // workspace layout (floats) — all cross-block data, coherent access only
    float* h0 = ws;             // [b*512+j]
    float* h1 = ws + 16384;
    float* xzr0 = ws + 32768;   // [b*1024+j]
    float* xg0 = ws + 65536;    // [b*512+j]  (reused as xg1 in phases C/D)
    float* z0 = ws + 81920;
    float* rh0 = ws + 98304;
    float* hzr1 = ws + 114688;  // [b*1024+j]
    float* z1 = ws + 147456;
    float* rh1 = ws + 163840;
    float* xg1 = xg0;           // alias: xg0 dead after B, xg1 live C->D

    // ---- pre-loop ----
    if (wg < 86) {
        for (int i = wg * NT + tid; i < 2 * Bq * Hq; i += 86 * NT) {
            int b = i >> 10, l = (i >> 9) & 1, j = i & 511;
            st_coh((l ? h1 : h0) + b * Hq + j, h0in[i]);
        }
    } else {
        stage128p(sst, x, (long)Sq * Iq);  // x_0
        int lid = (wg - 86) * NT + tid;
        if (lid < Bq * 2 * Hq) {
            int b = lid & 31, j = lid >> 5;
            st_coh(xzr0 + b * 1024 + j, dotC(sst, Wx0 + j * Iq, b, Iq));
        }
    }
    gridbar(bar, ++ep);

    for (int t = 0;; ++t) {
        // ---- phase A (epilogue at t==S) ----
        if (t == Sq) {
            if (wg < 128) {
                int i = wg * NT + tid;  // 32768 = B*L*H
                int b = i >> 10, l = (i >> 9) & 1, j = i & 511;
                out[(size_t)Bq * Sq * Oq + i] = ld_coh((l ? h1 : h0) + b * Hq + j);
            } else if (wg >= 240) {
                int lid = (wg - 240) * NT + tid;  // 4096 = B*O
                int b = lid & 31, o = lid >> 5;
                float acc = 0.f;
                for (int kb = 0; kb < Hq; kb += KB) {
                    stage256(sst, h1, Hq, kb);
                    acc += dotC(sst, Why + o * Hq + kb, b, KB);
                }
                out[((size_t)b * Sq + (Sq - 1)) * Oq + o] = acc + bhy[o];
            }
            break;
        }
        if (wg < 160) {
            // A1: z0, r0, rh0
            int lid = wg * NT + tid;
            bool act = lid < Bq * 2 * Hq;
            int b = lid & 31, j = lid >> 5;
            float acc = 0.f;
            for (int kb = 0; kb < Hq; kb += KB) {
                stage256(sst, h0, Hq, kb);
                if (act) acc += dotC(sst, Wh0 + j * Hq + kb, b, KB);
            }
            if (act) {
                float s = sigmoidf_(ld_coh(xzr0 + b * 1024 + j) + acc + bh0[j]);
                if (j < Hq)
                    st_coh(z0 + b * Hq + j, s);
                else
                    st_coh(rh0 + b * Hq + (j - Hq),
                           s * ld_coh(h0 + b * Hq + (j - Hq)));
            }
        } else if (wg < 240) {
            // A2: xg0 = x_t @ Wx0_g^T
            stage128p(sst, x + (long)t * Iq, (long)Sq * Iq);
            int lid = (wg - 160) * NT + tid;
            if (lid < Bq * Hq) {
                int b = lid & 31, j = lid >> 5;
                st_coh(xg0 + b * Hq + j,
                       dotC(sst, Wx0 + (2 * Hq + j) * Iq, b, Iq));
            }
        } else {
            // A3: y_{t-1}
            int lid = (wg - 240) * NT + tid;
            int b = lid & 31, o = lid >> 5;
            float acc = 0.f;
            for (int kb = 0; kb < Hq; kb += KB) {
                stage256(sst, h1, Hq, kb);
                acc += dotC(sst, Why + o * Hq + kb, b, KB);
            }
            if (t > 0)
                out[((size_t)b * Sq + (t - 1)) * Oq + o] = acc + bhy[o];
        }
        gridbar(bar, ++ep);

        // ---- phase B ----
        if (wg < 86) {
            // B1: g0, h0 update
            int lid = wg * NT + tid;
            bool act = lid < Bq * Hq;
            int b = lid & 31, j = lid >> 5;
            float acc = 0.f;
            for (int kb = 0; kb < Hq; kb += KB) {
                stage256(sst, rh0, Hq, kb);
                if (act) acc += dotC(sst, Wh0 + (2 * Hq + j) * Hq + kb, b, KB);
            }
            if (act) {
                float g = tanhf(ld_coh(xg0 + b * Hq + j) + acc + bh0[2 * Hq + j]);
                float zz = ld_coh(z0 + b * Hq + j);
                float hold = ld_coh(h0 + b * Hq + j);
                st_coh(h0 + b * Hq + j, zz * hold + (1.f - zz) * g);
            }
        } else {
            // B2: hzr1 = h1 @ Wh1_zr^T + bh1_zr
            int lid = (wg - 86) * NT + tid;
            bool act = lid < Bq * 2 * Hq;
            int b = lid & 31, j = lid >> 5;
            float acc = 0.f;
            for (int kb = 0; kb < Hq; kb += KB) {
                stage256(sst, h1, Hq, kb);
                if (act) acc += dotC(sst, Wh1 + j * Hq + kb, b, KB);
            }
            if (act) st_coh(hzr1 + b * 1024 + j, acc + bh1[j]);
        }
        gridbar(bar, ++ep);

        // ---- phase C: consume updated h0 (= s0) ----
        {
            bool isC1 = wg < 170;
            int lid = isC1 ? wg * NT + tid : (wg - 170) * NT + tid;
            int nout = isC1 ? Bq * 2 * Hq : Bq * Hq;
            bool act = lid < nout;
            int b = lid & 31, j = lid >> 5;
            const float* Wrow =
                isC1 ? (Wx1 + j * Hq) : (Wx1 + (2 * Hq + j) * Hq);
            float acc = 0.f;
            for (int kb = 0; kb < Hq; kb += KB) {
                stage256(sst, h0, Hq, kb);
                if (act) acc += dotC(sst, Wrow + kb, b, KB);
            }
            if (act) {
                if (isC1) {
                    float s = sigmoidf_(acc + ld_coh(hzr1 + b * 1024 + j));
                    if (j < Hq)
                        st_coh(z1 + b * Hq + j, s);
                    else
                        st_coh(rh1 + b * Hq + (j - Hq),
                               s * ld_coh(h1 + b * Hq + (j - Hq)));
                } else {
                    st_coh(xg1 + b * Hq + j, acc);
                }
            }
        }
        gridbar(bar, ++ep);

        // ---- phase D ----
        if (wg < 86) {
            // D1: g1, h1 update
            int lid = wg * NT + tid;
            bool act = lid < Bq * Hq;
            int b = lid & 31, j = lid >> 5;
            float acc = 0.f;
            for (int kb = 0; kb < Hq; kb += KB) {
                stage256(sst, rh1, Hq, kb);
                if (act) acc += dotC(sst, Wh1 + (2 * Hq + j) * Hq + kb, b, KB);
            }
            if (act) {
                float g = tanhf(ld_coh(xg1 + b * Hq + j) + acc + bh1[2 * Hq + j]);
                float zz = ld_coh(z1 + b * Hq + j);
                float hold = ld_coh(h1 + b * Hq + j);
                st_coh(h1 + b * Hq + j, zz * hold + (1.f - zz) * g);
            }
        } else if (t + 1 < Sq) {
            // D2: xzr0 for t+1
            stage128p(sst, x + (long)(t + 1) * Iq, (long)Sq * Iq);
            int lid = (wg - 86) * NT + tid;
            if (lid < Bq * 2 * Hq) {
                int b = lid & 31, j = lid >> 5;
                st_coh(xzr0 + b * 1024 + j, dotC(sst, Wx0 + j * Iq, b, Iq));
            }
        }
        gridbar(bar, ++ep);
    }
}

extern "C" void kernel_launch(void* const* d_in, const int* in_sizes, int n_in,
                              void* d_out, int out_size, void* d_ws,
                              size_t ws_size, hipStream_t stream) {
    const float* x = (const float*)d_in[0];
    const float* h0in = (const float*)d_in[1];
    const float* Wx0 = (const float*)d_in[2];
    const float* Wh0 = (const float*)d_in[3];
    const float* bh0 = (const float*)d_in[4];
    const float* Wx1 = (const float*)d_in[5];
    const float* Wh1 = (const float*)d_in[6];
    const float* bh1 = (const float*)d_in[7];
    const float* Why = (const float*)d_in[8];
    const float* bhy = (const float*)d_in[9];
    float* out = (float*)d_out;
    float* ws = (float*)d_ws;
    int* bar = (int*)(ws + 180224);

    bar_init<<<1, 256, 0, stream>>>(bar);
    gru_fused<<<dim3(NWG), dim3(NT), 0, stream>>>(x, h0in, Wx0, Wh0, bh0, Wx1,
                                                  Wh1, bh1, Why, bhy, out, ws);
}